// Round 11
// baseline (215.914 us; speedup 1.0000x reference)
//
#include <hip/hip_runtime.h>
#include <math.h>

// Problem constants: B=4, NF=64, H=W=128, K=9
// d_in order: nbr, ref, w1, b1, w2, b2, w3, b3, w_off, b_off, w_dcn, b_dcn
// d_out: feat [4,64,128,128] | offset [4,18,128,128] | mask [4,9,128,128]

typedef _Float16 h8 __attribute__((ext_vector_type(8)));  // 8 f16 (4 VGPRs)
typedef _Float16 h4 __attribute__((ext_vector_type(4)));  // 4 f16 (2 VGPRs)
typedef _Float16 h2 __attribute__((ext_vector_type(2)));  // packed f16 pair
typedef float f4 __attribute__((ext_vector_type(4)));     // 4 fp32 acc

// ================ merged setup: weight prep + border zero + input prep ================
__global__ __launch_bounds__(256) void setup_kernel(
    const float* __restrict__ nbr, const float* __restrict__ refp,
    const float* __restrict__ w1, const float* __restrict__ w2,
    const float* __restrict__ w3, const float* __restrict__ w_off,
    const float* __restrict__ w_dcn,
    _Float16* __restrict__ X1, _Float16* __restrict__ X2,
    _Float16* __restrict__ B64, _Float16* __restrict__ C64,
    _Float16* __restrict__ wF1, _Float16* __restrict__ wF2,
    _Float16* __restrict__ wF3, _Float16* __restrict__ wFo,
    _Float16* __restrict__ wFd) {
  __shared__ float t[64 * 65];
  int bid = blockIdx.x;
  int tid = threadIdx.x;
  if (bid < 792) {
    int i = bid * 256 + tid;
    // conv weights -> A-frag contiguous [tap*NCH+c][ocH][mt][lane][8]:
    // one wave A-load = 1KB coalesced.
    if (i < 73728) {                       // w1 (NCH=4, 128 IC)
      int j = i;
      int e = j & 7; int Lx = (j >> 3) & 63; int mt = (j >> 9) & 1; int wvx = (j >> 10) & 1;
      int pc = j >> 11;                    // tap*4+c
      int tap = pc >> 2, c = pc & 3;
      int oc = wvx * 32 + mt * 16 + (Lx & 15);
      int ic = c * 32 + ((Lx >> 4) << 3) + e;
      wF1[j] = (_Float16)w1[(oc * 128 + ic) * 9 + tap];
    } else if (i < 110592) {               // w2
      int j = i - 73728;
      int e = j & 7; int Lx = (j >> 3) & 63; int mt = (j >> 9) & 1; int wvx = (j >> 10) & 1;
      int pc = j >> 11;                    // tap*2+c
      int tap = pc >> 1, c = pc & 1;
      int oc = wvx * 32 + mt * 16 + (Lx & 15);
      int ic = c * 32 + ((Lx >> 4) << 3) + e;
      wF2[j] = (_Float16)w2[(oc * 64 + ic) * 9 + tap];
    } else if (i < 147456) {               // w3
      int j = i - 110592;
      int e = j & 7; int Lx = (j >> 3) & 63; int mt = (j >> 9) & 1; int wvx = (j >> 10) & 1;
      int pc = j >> 11;
      int tap = pc >> 1, c = pc & 1;
      int oc = wvx * 32 + mt * 16 + (Lx & 15);
      int ic = c * 32 + ((Lx >> 4) << 3) + e;
      wF3[j] = (_Float16)w3[(oc * 64 + ic) * 9 + tap];
    } else if (i < 165888) {               // w_off -> A-frag contiguous [tap*2+c][mt][lane][8]
      int jj = i - 147456;                 // 18432 = 18 * 1024
      int pc = jj >> 10;                   // tap*2+c
      int mt = (jj >> 9) & 1;
      int Lx = (jj >> 3) & 63;
      int e  = jj & 7;
      int tap = pc >> 1, c = pc & 1;
      int oc = mt * 16 + (Lx & 15);
      int ic = c * 32 + (Lx >> 4) * 8 + e;
      float v = (oc < 27) ? w_off[(oc * 64 + ic) * 9 + tap] : 0.f;
      wFo[jj] = (_Float16)v;
    } else if (i < 202752) {               // w_dcn -> A-frag contiguous [k*2+s][mt 4][lane][8]
      int jj = i - 165888;                 // 36864 = 18 * 2048
      int ks = jj >> 11;                   // k*2+s
      int mt = (jj >> 9) & 3;
      int Lx = (jj >> 3) & 63;
      int e  = jj & 7;
      int k = ks >> 1, s = ks & 1;
      int oc = mt * 16 + (Lx & 15);
      int ch = s * 32 + (Lx >> 4) * 8 + e;
      wFd[jj] = (_Float16)w_dcn[(oc * 64 + ch) * 9 + k];
    }
    return;
  }
  if (bid < 1050) {
    int i = (bid - 792) * 256 + tid;       // 66048 = 4 buf * 4 b * 516 px * 8 chunks
    int bufi = i / 16512;
    int j = i - bufi * 16512;
    int b = j / 4128;
    int r = j - b * 4128;
    int p = r >> 3; int cg = r & 7;
    int row, col;
    if (p < 130)      { row = 0;   col = p; }
    else if (p < 260) { row = 129; col = p - 130; }
    else if (p < 388) { row = 1 + (p - 260); col = 0; }
    else              { row = 1 + (p - 388); col = 129; }
    _Float16* dst = (bufi == 0) ? X1 : (bufi == 1) ? X2 : (bufi == 2) ? B64 : C64;
    uint4 z; z.x = z.y = z.z = z.w = 0u;
    *(uint4*)(dst + ((size_t)(b * 130 + row) * 130 + col) * 64 + cg * 8) = z;
    return;
  }
  // ---- input prep: fp32 NCHW -> padded NHWC f16 (64-px half-rows)
  int j = bid - 1050;                      // 2048 = 2 src * 4 b * 128 y * 2 half
  int half = j & 1;
  int y = (j >> 1) & 127;
  int b = (j >> 8) & 3;
  int src = j >> 10;
  const float* sp = src ? refp : nbr;
  _Float16* dst = src ? X2 : X1;
  for (int l = tid; l < 64 * 64; l += 256) {
    int c = l >> 6, gx = l & 63;
    t[c * 65 + gx] = sp[(((size_t)b * 64 + c) << 14) + (y << 7) + half * 64 + gx];
  }
  __syncthreads();
  unsigned* dstU = (unsigned*)dst;
  for (int l = tid; l < 64 * 32; l += 256) {
    int pxl = l >> 5, c2 = l & 31;
    union { _Float16 h[2]; unsigned u; } pk;
    pk.h[0] = (_Float16)t[(2 * c2) * 65 + pxl];
    pk.h[1] = (_Float16)t[(2 * c2 + 1) * 65 + pxl];
    dstU[((size_t)(b * 130 + y + 1) * 130 + 1 + half * 64 + pxl) * 32 + c2] = pk.u;
  }
}

// ================ LDS-staged conv, 4-wave quadrant split (r8 form, FROZEN).
template <int NCH, bool SPLIT>
__global__ __launch_bounds__(256, 4) void conv3x3_lds_kernel(
    const _Float16* __restrict__ X1, const _Float16* __restrict__ X2,
    const _Float16* __restrict__ W, const float* __restrict__ bias,
    _Float16* __restrict__ outP) {
  __shared__ _Float16 Lb[3 * 72 * 64];    // 27648 B slab [row 3][px 72][ch 64], swizzled
  int tid = threadIdx.x;
  int wv = tid >> 6, L = tid & 63;
  int lm = L & 15, lq = L >> 4;
  int ocH = wv >> 1, pxH = wv & 1;        // wave quadrant
  int bid = blockIdx.x;                   // 1024 = 8 xcd * (2 half * 16 ystrip * 4 b)
  int xcd = bid & 7, j = bid >> 3;
  int half = j & 1;
  int y = (xcd << 4) | ((j >> 1) & 15);
  int b = j >> 5;
  int px0 = half * 64;
  int pxq = pxH * 32;                     // wave's px offset within the slab

  auto stage = [&](const _Float16* Xsrc) {
    const char* Xb = (const char*)Xsrc;
    size_t rb0 = ((size_t)(b * 130 + y) * 130 + px0) * 128;  // byte offset of slab row 0
    for (int i = wv; i < 27; i += 4) {
      int o = i * 1024 + L * 16;
      int row = o / 9216;                 // 9216 = 72 px * 128 B
      int orow = o - row * 9216;
      int px = orow >> 7;
      int c2 = (orow >> 4) & 7;
      size_t src = rb0 + (size_t)row * 16640 + (size_t)(px << 7) + (((c2 ^ (px & 7))) << 4);
      __builtin_amdgcn_global_load_lds(
          (const __attribute__((address_space(1))) void*)(Xb + src),
          (__attribute__((address_space(3))) void*)((char*)Lb + i * 1024), 16, 0, 0);
    }
  };

  f4 acc[2][2];
#pragma unroll
  for (int m = 0; m < 2; ++m)
#pragma unroll
    for (int n = 0; n < 2; ++n) acc[m][n] = (f4)0.f;

  auto compute = [&](int cbase) {
#pragma unroll
    for (int ci = 0; ci < 2; ++ci) {
      int c = cbase + ci;
#pragma unroll
      for (int tg = 0; tg < 3; ++tg) {
        h8 a[6];
#pragma unroll
        for (int t = 0; t < 3; ++t) {
          int tap = tg * 3 + t;
          const _Float16* wp = W + (size_t)((tap * NCH + c) * 2 + ocH) * 1024 + L * 8;
          a[2 * t]     = *(const h8*)(wp);
          a[2 * t + 1] = *(const h8*)(wp + 512);
        }
#pragma unroll
        for (int t = 0; t < 3; ++t) {
          int tap = tg * 3 + t;
          const int dy = tap / 3, dx = tap % 3;
          h8 bf[2];
#pragma unroll
          for (int g = 0; g < 2; ++g) {
            int pxcol = pxq + g * 16 + lm + dx;
            int chunk = (ci * 4 + lq) ^ (pxcol & 7);
            int off = dy * 9216 + (pxcol << 7) + (chunk << 4);
            bf[g] = *(const h8*)((const char*)Lb + off);
          }
#pragma unroll
          for (int g = 0; g < 2; ++g) {
            acc[0][g] = __builtin_amdgcn_mfma_f32_16x16x32_f16(a[2 * t], bf[g], acc[0][g], 0, 0, 0);
            acc[1][g] = __builtin_amdgcn_mfma_f32_16x16x32_f16(a[2 * t + 1], bf[g], acc[1][g], 0, 0, 0);
          }
        }
      }
    }
  };

  stage(X1);
  asm volatile("s_waitcnt vmcnt(0)" ::: "memory");
  __syncthreads();
  compute(0);
  if (SPLIT) {
    __syncthreads();
    stage(X2);
    asm volatile("s_waitcnt vmcnt(0)" ::: "memory");
    __syncthreads();
    compute(2);
  }

  const size_t obase = ((size_t)(b * 130 + (y + 1)) * 130 + 1 + px0) * 64;
#pragma unroll
  for (int mt = 0; mt < 2; ++mt)
#pragma unroll
    for (int nt = 0; nt < 2; ++nt) {
      int px = pxq + nt * 16 + lm;
      h4 pk;
#pragma unroll
      for (int r = 0; r < 4; ++r) {
        int oc = ocH * 32 + mt * 16 + lq * 4 + r;
        float v = acc[mt][nt][r] + bias[oc];
        v = (v >= 0.f) ? v : 0.1f * v;
        pk[r] = (_Float16)v;
      }
      *(h4*)(outP + obase + (size_t)px * 64 + ocH * 32 + mt * 16 + lq * 4) = pk;
    }
}

// ================ FUSED conv_off + DCN (r7/r8 form) + NT probe on gathers.
// Gather-wall model: 4.7M 64B segments x ~8.2 cyc/seg/CU. After line-pairing there
// is ZERO residual L1 reuse on the gather stream -> if the per-segment cost is L1
// allocation/fill, `nt` (non-temporal, no L1 allocate) removes it; if it is TA
// address-issue (16 distinct segments/instr, fixed), nt is neutral and the wall
// is confirmed structural. Phase-1 loads keep normal caching (halo reuse).
__global__ __launch_bounds__(256, 4) void off_dcn_kernel(
    const _Float16* __restrict__ Xc, const _Float16* __restrict__ Xs,
    const _Float16* __restrict__ Wo, const float* __restrict__ bo,
    const _Float16* __restrict__ wD, const float* __restrict__ bd,
    float* __restrict__ off_out, float* __restrict__ mask_out,
    float* __restrict__ out) {
  __shared__ float Soff[4][16][28];     // per-WAVE slice: [px][0..17]=off, [18..26]=mask
  int tid = threadIdx.x;
  int wv = tid >> 6, L = tid & 63;
  int lm = L & 15, lq = L >> 4;
  int lq8 = lq * 8;
  int g = blockIdx.x;                   // 1024 = 8 xcd * (2 half * 16 ystrip * 4 b)
  int xcd = g & 7;
  int r0 = g >> 3;
  int half = r0 & 1;
  int y = (xcd << 4) | ((r0 >> 1) & 15);
  int b = r0 >> 5;
  int px0 = half * 64 + wv * 16;        // wave's 16-px tile base
  int gpx = px0 + lm;                   // this lane's pixel
  int hw = (y << 7) + gpx;
  int rb = b * 130;

  // ---- phase 1: conv_off (32 oc x 16 px), 9-deep batched input loads per c
  {
    f4 oa[2];
    oa[0] = (f4)0.f; oa[1] = (f4)0.f;
#pragma unroll
    for (int c = 0; c < 2; ++c) {
      const void* pB[9];
#pragma unroll
      for (int tap = 0; tap < 9; ++tap) {
        const int dy = tap / 3 - 1, dx = tap % 3 - 1;
        pB[tap] = (const void*)(Xc + ((size_t)((rb + (y + 1 + dy)) * 130) + (1 + dx) + px0 + lm) * 64
                                   + c * 32 + lq8);
      }
      h8 bq[9];
      asm volatile(
          "global_load_dwordx4 %0, %9, off\n\t"
          "global_load_dwordx4 %1, %10, off\n\t"
          "global_load_dwordx4 %2, %11, off\n\t"
          "global_load_dwordx4 %3, %12, off\n\t"
          "global_load_dwordx4 %4, %13, off\n\t"
          "global_load_dwordx4 %5, %14, off\n\t"
          "global_load_dwordx4 %6, %15, off\n\t"
          "global_load_dwordx4 %7, %16, off\n\t"
          "global_load_dwordx4 %8, %17, off\n\t"
          "s_waitcnt vmcnt(0)"
          : "=&v"(bq[0]), "=&v"(bq[1]), "=&v"(bq[2]), "=&v"(bq[3]), "=&v"(bq[4]),
            "=&v"(bq[5]), "=&v"(bq[6]), "=&v"(bq[7]), "=&v"(bq[8])
          : "v"(pB[0]), "v"(pB[1]), "v"(pB[2]), "v"(pB[3]), "v"(pB[4]),
            "v"(pB[5]), "v"(pB[6]), "v"(pB[7]), "v"(pB[8])
          : "memory");
#pragma unroll
      for (int tap = 0; tap < 9; ++tap) {
        const _Float16* wp = Wo + (size_t)(tap * 2 + c) * 1024 + L * 8;
        h8 a0 = *(const h8*)(wp);
        h8 a1 = *(const h8*)(wp + 512);
        oa[0] = __builtin_amdgcn_mfma_f32_16x16x32_f16(a0, bq[tap], oa[0], 0, 0, 0);
        oa[1] = __builtin_amdgcn_mfma_f32_16x16x32_f16(a1, bq[tap], oa[1], 0, 0, 0);
      }
    }
#pragma unroll
    for (int mt = 0; mt < 2; ++mt)
#pragma unroll
      for (int r = 0; r < 4; ++r) {
        int oc = mt * 16 + lq * 4 + r;
        if (oc < 18) {
          float v = 15.f * tanhf(oa[mt][r] + bo[oc]);
          off_out[((b * 18 + oc) << 14) + hw] = v;
          Soff[wv][lm][oc] = v;
        } else if (oc < 27) {
          float v = 1.f / (1.f + expf(-(oa[mt][r] + bo[oc])));
          mask_out[((b * 9 + (oc - 18)) << 14) + hw] = v;
          Soff[wv][lm][oc] = v;
        }
      }
  }
  // no __syncthreads: Soff slice is written and read by the SAME wave (lgkmcnt order).

  // ---- phase 2: DCN, 9 taps; per tap ONE asm batch: 4 corner addrs x {0,64} pairs, NT
  f4 acc[4];
#pragma unroll
  for (int mm = 0; mm < 4; ++mm) acc[mm] = (f4)0.f;

  const char* Xb = (const char*)Xs;
  const int cbL = lq8 * 2;              // lane channel byte offset within pixel block

#pragma unroll
  for (int k = 0; k < 9; ++k) {
    const int kr = k / 3, kc = k - kr * 3;
    float oy = Soff[wv][lm][2 * k];
    float ox = Soff[wv][lm][2 * k + 1];
    float mk = Soff[wv][lm][18 + k];
    float py = (float)(y + kr - 1) + oy;
    float pxf = (float)(gpx + kc - 1) + ox;
    float fy = floorf(py), fx = floorf(pxf);
    float wy = py - fy, wx = pxf - fx;
    int y0 = (int)fy, x0 = (int)fx;
    int y1 = y0 + 1, x1 = x0 + 1;
    float vy0 = ((unsigned)y0 < 128u) ? 1.f : 0.f;
    float vy1 = ((unsigned)y1 < 128u) ? 1.f : 0.f;
    float vx0 = ((unsigned)x0 < 128u) ? 1.f : 0.f;
    float vx1 = ((unsigned)x1 < 128u) ? 1.f : 0.f;
    float ey = 1.f - wy, ex = 1.f - wx;
    _Float16 w00 = (_Float16)(ey * ex * mk * vy0 * vx0);
    _Float16 w01 = (_Float16)(ey * wx * mk * vy0 * vx1);
    _Float16 w10 = (_Float16)(wy * ex * mk * vy1 * vx0);
    _Float16 w11 = (_Float16)(wy * wx * mk * vy1 * vx1);
    h2 W00 = {w00, w00}, W01 = {w01, w01}, W10 = {w10, w10}, W11 = {w11, w11};
    int y0c = min(max(y0, 0), 127) + 1, y1c = min(max(y1, 0), 127) + 1;
    int x0c = min(max(x0, 0), 127) + 1, x1c = min(max(x1, 0), 127) + 1;
    const void* a00 = (const void*)(Xb + (rb + y0c) * 16640 + x0c * 128 + cbL);
    const void* a01 = (const void*)(Xb + (rb + y0c) * 16640 + x1c * 128 + cbL);
    const void* a10 = (const void*)(Xb + (rb + y1c) * 16640 + x0c * 128 + cbL);
    const void* a11 = (const void*)(Xb + (rb + y1c) * 16640 + x1c * 128 + cbL);
    h8 gv[8];                           // [corner 4][s 2]: gv[2c+s]
    asm volatile(
        "global_load_dwordx4 %0, %8, off nt\n\t"
        "global_load_dwordx4 %1, %8, off offset:64 nt\n\t"
        "global_load_dwordx4 %2, %9, off nt\n\t"
        "global_load_dwordx4 %3, %9, off offset:64 nt\n\t"
        "global_load_dwordx4 %4, %10, off nt\n\t"
        "global_load_dwordx4 %5, %10, off offset:64 nt\n\t"
        "global_load_dwordx4 %6, %11, off nt\n\t"
        "global_load_dwordx4 %7, %11, off offset:64 nt\n\t"
        "s_waitcnt vmcnt(0)"
        : "=&v"(gv[0]), "=&v"(gv[1]), "=&v"(gv[2]), "=&v"(gv[3]),
          "=&v"(gv[4]), "=&v"(gv[5]), "=&v"(gv[6]), "=&v"(gv[7])
        : "v"(a00), "v"(a01), "v"(a10), "v"(a11)
        : "memory");
#pragma unroll
    for (int s = 0; s < 2; ++s) {
      h8 bv;
#pragma unroll
      for (int j2 = 0; j2 < 4; ++j2) {
        h2 a  = {gv[0 + s][2 * j2], gv[0 + s][2 * j2 + 1]};
        h2 bb = {gv[2 + s][2 * j2], gv[2 + s][2 * j2 + 1]};
        h2 cc = {gv[4 + s][2 * j2], gv[4 + s][2 * j2 + 1]};
        h2 dd = {gv[6 + s][2 * j2], gv[6 + s][2 * j2 + 1]};
        h2 r = a * W00;
        r += bb * W01;
        r += cc * W10;
        r += dd * W11;
        bv[2 * j2] = r[0];
        bv[2 * j2 + 1] = r[1];
      }
      const _Float16* wp = wD + (size_t)(k * 2 + s) * 2048 + L * 8;
      acc[0] = __builtin_amdgcn_mfma_f32_16x16x32_f16(*(const h8*)(wp), bv, acc[0], 0, 0, 0);
      acc[1] = __builtin_amdgcn_mfma_f32_16x16x32_f16(*(const h8*)(wp + 512), bv, acc[1], 0, 0, 0);
      acc[2] = __builtin_amdgcn_mfma_f32_16x16x32_f16(*(const h8*)(wp + 1024), bv, acc[2], 0, 0, 0);
      acc[3] = __builtin_amdgcn_mfma_f32_16x16x32_f16(*(const h8*)(wp + 1536), bv, acc[3], 0, 0, 0);
    }
  }

  // epilogue: bias + lrelu, fp32 NCHW
#pragma unroll
  for (int mt = 0; mt < 4; ++mt)
#pragma unroll
    for (int r = 0; r < 4; ++r) {
      int oc = mt * 16 + lq * 4 + r;
      float v = acc[mt][r] + bd[oc];
      v = (v >= 0.f) ? v : 0.1f * v;
      out[(((b << 6) + oc) << 14) + (y << 7) + gpx] = v;
    }
}

extern "C" void kernel_launch(void* const* d_in, const int* in_sizes, int n_in,
                              void* d_out, int out_size, void* d_ws, size_t ws_size,
                              hipStream_t stream) {
  const float* nbr   = (const float*)d_in[0];
  const float* refp  = (const float*)d_in[1];
  const float* w1    = (const float*)d_in[2];
  const float* b1    = (const float*)d_in[3];
  const float* w2    = (const float*)d_in[4];
  const float* b2    = (const float*)d_in[5];
  const float* w3    = (const float*)d_in[6];
  const float* b3    = (const float*)d_in[7];
  const float* w_off = (const float*)d_in[8];
  const float* b_off = (const float*)d_in[9];
  const float* w_dcn = (const float*)d_in[10];
  const float* b_dcn = (const float*)d_in[11];

  float* outp = (float*)d_out;
  float* feat = outp;                       // 4*64*16384
  float* offp = outp + 4194304;             // 4*18*16384
  float* mskp = outp + 4194304 + 1179648;   // 4*9*16384

  // ws layout: four padded NHWC f16 buffers [4][130][130][64] + f16 weights (~33.4 MiB)
  char* ws = (char*)d_ws;
  const size_t PB = 8652800;                // bytes per padded buffer
  _Float16* X1  = (_Float16*)ws;            // nbr padded (conv1 in + DCN sample src)
  _Float16* X2  = (_Float16*)(ws + PB);     // ref padded
  _Float16* B64 = (_Float16*)(ws + 2 * PB); // conv1 out / conv3 out
  _Float16* C64 = (_Float16*)(ws + 3 * PB); // conv2 out
  char* p = ws + 4 * PB;
  _Float16* wF1 = (_Float16*)p;  p += (size_t)73728 * 2;
  _Float16* wF2 = (_Float16*)p;  p += (size_t)36864 * 2;
  _Float16* wF3 = (_Float16*)p;  p += (size_t)36864 * 2;
  _Float16* wFo = (_Float16*)p;  p += (size_t)18432 * 2;
  _Float16* wFd = (_Float16*)p;

  // 5 dispatches total
  setup_kernel<<<dim3(3098), 256, 0, stream>>>(nbr, refp, w1, w2, w3, w_off, w_dcn,
                                               X1, X2, B64, C64, wF1, wF2, wF3, wFo, wFd);
  conv3x3_lds_kernel<4, true><<<dim3(1024), 256, 0, stream>>>(X1, X2, wF1, b1, B64);
  conv3x3_lds_kernel<2, false><<<dim3(1024), 256, 0, stream>>>(B64, nullptr, wF2, b2, C64);
  conv3x3_lds_kernel<2, false><<<dim3(1024), 256, 0, stream>>>(C64, nullptr, wF3, b3, B64);
  off_dcn_kernel<<<dim3(1024), 256, 0, stream>>>(B64, X1, wFo, b_off, wFd, b_dcn,
                                                 offp, mskp, feat);
}

// Round 12
// 196.828 us; speedup vs baseline: 1.0970x; 1.0970x over previous
//
#include <hip/hip_runtime.h>
#include <math.h>

// Problem constants: B=4, NF=64, H=W=128, K=9
// d_in order: nbr, ref, w1, b1, w2, b2, w3, b3, w_off, b_off, w_dcn, b_dcn
// d_out: feat [4,64,128,128] | offset [4,18,128,128] | mask [4,9,128,128]

typedef _Float16 h8 __attribute__((ext_vector_type(8)));  // 8 f16 (4 VGPRs)
typedef _Float16 h4 __attribute__((ext_vector_type(4)));  // 4 f16 (2 VGPRs)
typedef _Float16 h2 __attribute__((ext_vector_type(2)));  // packed f16 pair
typedef float f4 __attribute__((ext_vector_type(4)));     // 4 fp32 acc

// ================ merged setup: weight prep + border zero + input prep ================
__global__ __launch_bounds__(256) void setup_kernel(
    const float* __restrict__ nbr, const float* __restrict__ refp,
    const float* __restrict__ w1, const float* __restrict__ w2,
    const float* __restrict__ w3, const float* __restrict__ w_off,
    const float* __restrict__ w_dcn,
    _Float16* __restrict__ X1, _Float16* __restrict__ X2,
    _Float16* __restrict__ B64, _Float16* __restrict__ C64,
    _Float16* __restrict__ wF1, _Float16* __restrict__ wF2,
    _Float16* __restrict__ wF3, _Float16* __restrict__ wFo,
    _Float16* __restrict__ wFd) {
  __shared__ float t[64 * 65];
  int bid = blockIdx.x;
  int tid = threadIdx.x;
  if (bid < 792) {
    int i = bid * 256 + tid;
    // conv weights -> A-frag contiguous [tap*NCH+c][ocH][mt][lane][8]:
    // one wave A-load = coalesced; ocQ = ocH*2+mt indexes 16-oc fragments (stride 512).
    if (i < 73728) {                       // w1 (NCH=4, 128 IC)
      int j = i;
      int e = j & 7; int Lx = (j >> 3) & 63; int mt = (j >> 9) & 1; int wvx = (j >> 10) & 1;
      int pc = j >> 11;                    // tap*4+c
      int tap = pc >> 2, c = pc & 3;
      int oc = wvx * 32 + mt * 16 + (Lx & 15);
      int ic = c * 32 + ((Lx >> 4) << 3) + e;
      wF1[j] = (_Float16)w1[(oc * 128 + ic) * 9 + tap];
    } else if (i < 110592) {               // w2
      int j = i - 73728;
      int e = j & 7; int Lx = (j >> 3) & 63; int mt = (j >> 9) & 1; int wvx = (j >> 10) & 1;
      int pc = j >> 11;                    // tap*2+c
      int tap = pc >> 1, c = pc & 1;
      int oc = wvx * 32 + mt * 16 + (Lx & 15);
      int ic = c * 32 + ((Lx >> 4) << 3) + e;
      wF2[j] = (_Float16)w2[(oc * 64 + ic) * 9 + tap];
    } else if (i < 147456) {               // w3
      int j = i - 110592;
      int e = j & 7; int Lx = (j >> 3) & 63; int mt = (j >> 9) & 1; int wvx = (j >> 10) & 1;
      int pc = j >> 11;
      int tap = pc >> 1, c = pc & 1;
      int oc = wvx * 32 + mt * 16 + (Lx & 15);
      int ic = c * 32 + ((Lx >> 4) << 3) + e;
      wF3[j] = (_Float16)w3[(oc * 64 + ic) * 9 + tap];
    } else if (i < 165888) {               // w_off -> A-frag contiguous [tap*2+c][mt][lane][8]
      int jj = i - 147456;                 // 18432 = 18 * 1024
      int pc = jj >> 10;                   // tap*2+c
      int mt = (jj >> 9) & 1;
      int Lx = (jj >> 3) & 63;
      int e  = jj & 7;
      int tap = pc >> 1, c = pc & 1;
      int oc = mt * 16 + (Lx & 15);
      int ic = c * 32 + (Lx >> 4) * 8 + e;
      float v = (oc < 27) ? w_off[(oc * 64 + ic) * 9 + tap] : 0.f;
      wFo[jj] = (_Float16)v;
    } else if (i < 202752) {               // w_dcn -> A-frag contiguous [k*2+s][mt 4][lane][8]
      int jj = i - 165888;                 // 36864 = 18 * 2048
      int ks = jj >> 11;                   // k*2+s
      int mt = (jj >> 9) & 3;
      int Lx = (jj >> 3) & 63;
      int e  = jj & 7;
      int k = ks >> 1, s = ks & 1;
      int oc = mt * 16 + (Lx & 15);
      int ch = s * 32 + (Lx >> 4) * 8 + e;
      wFd[jj] = (_Float16)w_dcn[(oc * 64 + ch) * 9 + k];
    }
    return;
  }
  if (bid < 1050) {
    int i = (bid - 792) * 256 + tid;       // 66048 = 4 buf * 4 b * 516 px * 8 chunks
    int bufi = i / 16512;
    int j = i - bufi * 16512;
    int b = j / 4128;
    int r = j - b * 4128;
    int p = r >> 3; int cg = r & 7;
    int row, col;
    if (p < 130)      { row = 0;   col = p; }
    else if (p < 260) { row = 129; col = p - 130; }
    else if (p < 388) { row = 1 + (p - 260); col = 0; }
    else              { row = 1 + (p - 388); col = 129; }
    _Float16* dst = (bufi == 0) ? X1 : (bufi == 1) ? X2 : (bufi == 2) ? B64 : C64;
    uint4 z; z.x = z.y = z.z = z.w = 0u;
    *(uint4*)(dst + ((size_t)(b * 130 + row) * 130 + col) * 64 + cg * 8) = z;
    return;
  }
  // ---- input prep: fp32 NCHW -> padded NHWC f16 (64-px half-rows)
  int j = bid - 1050;                      // 2048 = 2 src * 4 b * 128 y * 2 half
  int half = j & 1;
  int y = (j >> 1) & 127;
  int b = (j >> 8) & 3;
  int src = j >> 10;
  const float* sp = src ? refp : nbr;
  _Float16* dst = src ? X2 : X1;
  for (int l = tid; l < 64 * 64; l += 256) {
    int c = l >> 6, gx = l & 63;
    t[c * 65 + gx] = sp[(((size_t)b * 64 + c) << 14) + (y << 7) + half * 64 + gx];
  }
  __syncthreads();
  unsigned* dstU = (unsigned*)dst;
  for (int l = tid; l < 64 * 32; l += 256) {
    int pxl = l >> 5, c2 = l & 31;
    union { _Float16 h[2]; unsigned u; } pk;
    pk.h[0] = (_Float16)t[(2 * c2) * 65 + pxl];
    pk.h[1] = (_Float16)t[(2 * c2 + 1) * 65 + pxl];
    dstU[((size_t)(b * 130 + y + 1) * 130 + 1 + half * 64 + pxl) * 32 + c2] = pk.u;
  }
}

// ================ LDS-staged conv, 8-wave split for FULL occupancy.
// r8 ran 16 waves/CU (4 blocks x 4 waves); wave-tile 32oc x 32px caps total waves
// at 4096 = 16/CU. Shrink wave tile to 16oc x 32px -> 8192 waves: 1024 blocks x
// 512 thr (8 waves = 4 ocQ x 2 pxH), same 27.6KB slab, launch_bounds(512,8)
// (per-wave regs ~28 data + addressing <= 64) -> 4 blocks/CU x 8 waves =
// 32 waves/CU. Total MFMA count unchanged (2/wave-t instead of 4, 2x waves).
template <int NCH, bool SPLIT>
__global__ __launch_bounds__(512, 8) void conv3x3_lds_kernel(
    const _Float16* __restrict__ X1, const _Float16* __restrict__ X2,
    const _Float16* __restrict__ W, const float* __restrict__ bias,
    _Float16* __restrict__ outP) {
  __shared__ _Float16 Lb[3 * 72 * 64];    // 27648 B slab [row 3][px 72][ch 64], swizzled
  int tid = threadIdx.x;
  int wv = tid >> 6, L = tid & 63;
  int lm = L & 15, lq = L >> 4;
  int ocQ = wv >> 1, pxH = wv & 1;        // 8 waves: 4 oc quarters x 2 px halves
  int bid = blockIdx.x;                   // 1024 = 8 xcd * (2 half * 16 ystrip * 4 b)
  int xcd = bid & 7, j = bid >> 3;
  int half = j & 1;
  int y = (xcd << 4) | ((j >> 1) & 15);
  int b = j >> 5;
  int px0 = half * 64;
  int pxq = pxH * 32;                     // wave's px offset within the slab

  auto stage = [&](const _Float16* Xsrc) {
    const char* Xb = (const char*)Xsrc;
    size_t rb0 = ((size_t)(b * 130 + y) * 130 + px0) * 128;  // byte offset of slab row 0
    for (int i = wv; i < 27; i += 8) {
      int o = i * 1024 + L * 16;
      int row = o / 9216;                 // 9216 = 72 px * 128 B
      int orow = o - row * 9216;
      int px = orow >> 7;
      int c2 = (orow >> 4) & 7;
      size_t src = rb0 + (size_t)row * 16640 + (size_t)(px << 7) + (((c2 ^ (px & 7))) << 4);
      __builtin_amdgcn_global_load_lds(
          (const __attribute__((address_space(1))) void*)(Xb + src),
          (__attribute__((address_space(3))) void*)((char*)Lb + i * 1024), 16, 0, 0);
    }
  };

  f4 acc[2];
  acc[0] = (f4)0.f; acc[1] = (f4)0.f;

  auto compute = [&](int cbase) {
#pragma unroll
    for (int ci = 0; ci < 2; ++ci) {
      int c = cbase + ci;
#pragma unroll
      for (int tg = 0; tg < 3; ++tg) {
        h8 a[3];
#pragma unroll
        for (int t = 0; t < 3; ++t) {
          int tap = tg * 3 + t;
          a[t] = *(const h8*)(W + (size_t)(tap * NCH + c) * 2048 + ocQ * 512 + L * 8);
        }
#pragma unroll
        for (int t = 0; t < 3; ++t) {
          int tap = tg * 3 + t;
          const int dy = tap / 3, dx = tap % 3;
          h8 bf[2];
#pragma unroll
          for (int g = 0; g < 2; ++g) {
            int pxcol = pxq + g * 16 + lm + dx;
            int chunk = (ci * 4 + lq) ^ (pxcol & 7);
            int off = dy * 9216 + (pxcol << 7) + (chunk << 4);
            bf[g] = *(const h8*)((const char*)Lb + off);
          }
          acc[0] = __builtin_amdgcn_mfma_f32_16x16x32_f16(a[t], bf[0], acc[0], 0, 0, 0);
          acc[1] = __builtin_amdgcn_mfma_f32_16x16x32_f16(a[t], bf[1], acc[1], 0, 0, 0);
        }
      }
    }
  };

  stage(X1);
  asm volatile("s_waitcnt vmcnt(0)" ::: "memory");
  __syncthreads();
  compute(0);
  if (SPLIT) {
    __syncthreads();
    stage(X2);
    asm volatile("s_waitcnt vmcnt(0)" ::: "memory");
    __syncthreads();
    compute(2);
  }

  const size_t obase = ((size_t)(b * 130 + (y + 1)) * 130 + 1 + px0) * 64;
#pragma unroll
  for (int nt = 0; nt < 2; ++nt) {
    int px = pxq + nt * 16 + lm;
    h4 pk;
#pragma unroll
    for (int r = 0; r < 4; ++r) {
      int oc = ocQ * 16 + lq * 4 + r;
      float v = acc[nt][r] + bias[oc];
      v = (v >= 0.f) ? v : 0.1f * v;
      pk[r] = (_Float16)v;
    }
    *(h4*)(outP + obase + (size_t)px * 64 + ocQ * 16 + lq * 4) = pk;
  }
}

// ================ FUSED conv_off + DCN (r7/r8 form, FROZEN — gather wall is
// structural: nt probe (r11) showed L1/L2 absorb 95% of the 300MB gather stream;
// cost is the per-segment lookup path, ~8 cyc/64B seg, not fill or HBM).
__global__ __launch_bounds__(256, 4) void off_dcn_kernel(
    const _Float16* __restrict__ Xc, const _Float16* __restrict__ Xs,
    const _Float16* __restrict__ Wo, const float* __restrict__ bo,
    const _Float16* __restrict__ wD, const float* __restrict__ bd,
    float* __restrict__ off_out, float* __restrict__ mask_out,
    float* __restrict__ out) {
  __shared__ float Soff[4][16][28];     // per-WAVE slice: [px][0..17]=off, [18..26]=mask
  int tid = threadIdx.x;
  int wv = tid >> 6, L = tid & 63;
  int lm = L & 15, lq = L >> 4;
  int lq8 = lq * 8;
  int g = blockIdx.x;                   // 1024 = 8 xcd * (2 half * 16 ystrip * 4 b)
  int xcd = g & 7;
  int r0 = g >> 3;
  int half = r0 & 1;
  int y = (xcd << 4) | ((r0 >> 1) & 15);
  int b = r0 >> 5;
  int px0 = half * 64 + wv * 16;        // wave's 16-px tile base
  int gpx = px0 + lm;                   // this lane's pixel
  int hw = (y << 7) + gpx;
  int rb = b * 130;

  // ---- phase 1: conv_off (32 oc x 16 px), 9-deep batched input loads per c
  {
    f4 oa[2];
    oa[0] = (f4)0.f; oa[1] = (f4)0.f;
#pragma unroll
    for (int c = 0; c < 2; ++c) {
      const void* pB[9];
#pragma unroll
      for (int tap = 0; tap < 9; ++tap) {
        const int dy = tap / 3 - 1, dx = tap % 3 - 1;
        pB[tap] = (const void*)(Xc + ((size_t)((rb + (y + 1 + dy)) * 130) + (1 + dx) + px0 + lm) * 64
                                   + c * 32 + lq8);
      }
      h8 bq[9];
      asm volatile(
          "global_load_dwordx4 %0, %9, off\n\t"
          "global_load_dwordx4 %1, %10, off\n\t"
          "global_load_dwordx4 %2, %11, off\n\t"
          "global_load_dwordx4 %3, %12, off\n\t"
          "global_load_dwordx4 %4, %13, off\n\t"
          "global_load_dwordx4 %5, %14, off\n\t"
          "global_load_dwordx4 %6, %15, off\n\t"
          "global_load_dwordx4 %7, %16, off\n\t"
          "global_load_dwordx4 %8, %17, off\n\t"
          "s_waitcnt vmcnt(0)"
          : "=&v"(bq[0]), "=&v"(bq[1]), "=&v"(bq[2]), "=&v"(bq[3]), "=&v"(bq[4]),
            "=&v"(bq[5]), "=&v"(bq[6]), "=&v"(bq[7]), "=&v"(bq[8])
          : "v"(pB[0]), "v"(pB[1]), "v"(pB[2]), "v"(pB[3]), "v"(pB[4]),
            "v"(pB[5]), "v"(pB[6]), "v"(pB[7]), "v"(pB[8])
          : "memory");
#pragma unroll
      for (int tap = 0; tap < 9; ++tap) {
        const _Float16* wp = Wo + (size_t)(tap * 2 + c) * 1024 + L * 8;
        h8 a0 = *(const h8*)(wp);
        h8 a1 = *(const h8*)(wp + 512);
        oa[0] = __builtin_amdgcn_mfma_f32_16x16x32_f16(a0, bq[tap], oa[0], 0, 0, 0);
        oa[1] = __builtin_amdgcn_mfma_f32_16x16x32_f16(a1, bq[tap], oa[1], 0, 0, 0);
      }
    }
#pragma unroll
    for (int mt = 0; mt < 2; ++mt)
#pragma unroll
      for (int r = 0; r < 4; ++r) {
        int oc = mt * 16 + lq * 4 + r;
        if (oc < 18) {
          float v = 15.f * tanhf(oa[mt][r] + bo[oc]);
          off_out[((b * 18 + oc) << 14) + hw] = v;
          Soff[wv][lm][oc] = v;
        } else if (oc < 27) {
          float v = 1.f / (1.f + expf(-(oa[mt][r] + bo[oc])));
          mask_out[((b * 9 + (oc - 18)) << 14) + hw] = v;
          Soff[wv][lm][oc] = v;
        }
      }
  }
  // no __syncthreads: Soff slice is written and read by the SAME wave (lgkmcnt order).

  // ---- phase 2: DCN, 9 taps; per tap ONE asm batch: 4 corner addrs x {0,64} pairs
  f4 acc[4];
#pragma unroll
  for (int mm = 0; mm < 4; ++mm) acc[mm] = (f4)0.f;

  const char* Xb = (const char*)Xs;
  const int cbL = lq8 * 2;              // lane channel byte offset within pixel block

#pragma unroll
  for (int k = 0; k < 9; ++k) {
    const int kr = k / 3, kc = k - kr * 3;
    float oy = Soff[wv][lm][2 * k];
    float ox = Soff[wv][lm][2 * k + 1];
    float mk = Soff[wv][lm][18 + k];
    float py = (float)(y + kr - 1) + oy;
    float pxf = (float)(gpx + kc - 1) + ox;
    float fy = floorf(py), fx = floorf(pxf);
    float wy = py - fy, wx = pxf - fx;
    int y0 = (int)fy, x0 = (int)fx;
    int y1 = y0 + 1, x1 = x0 + 1;
    float vy0 = ((unsigned)y0 < 128u) ? 1.f : 0.f;
    float vy1 = ((unsigned)y1 < 128u) ? 1.f : 0.f;
    float vx0 = ((unsigned)x0 < 128u) ? 1.f : 0.f;
    float vx1 = ((unsigned)x1 < 128u) ? 1.f : 0.f;
    float ey = 1.f - wy, ex = 1.f - wx;
    _Float16 w00 = (_Float16)(ey * ex * mk * vy0 * vx0);
    _Float16 w01 = (_Float16)(ey * wx * mk * vy0 * vx1);
    _Float16 w10 = (_Float16)(wy * ex * mk * vy1 * vx0);
    _Float16 w11 = (_Float16)(wy * wx * mk * vy1 * vx1);
    h2 W00 = {w00, w00}, W01 = {w01, w01}, W10 = {w10, w10}, W11 = {w11, w11};
    int y0c = min(max(y0, 0), 127) + 1, y1c = min(max(y1, 0), 127) + 1;
    int x0c = min(max(x0, 0), 127) + 1, x1c = min(max(x1, 0), 127) + 1;
    const void* a00 = (const void*)(Xb + (rb + y0c) * 16640 + x0c * 128 + cbL);
    const void* a01 = (const void*)(Xb + (rb + y0c) * 16640 + x1c * 128 + cbL);
    const void* a10 = (const void*)(Xb + (rb + y1c) * 16640 + x0c * 128 + cbL);
    const void* a11 = (const void*)(Xb + (rb + y1c) * 16640 + x1c * 128 + cbL);
    h8 gv[8];                           // [corner 4][s 2]: gv[2c+s]
    asm volatile(
        "global_load_dwordx4 %0, %8, off\n\t"
        "global_load_dwordx4 %1, %8, off offset:64\n\t"
        "global_load_dwordx4 %2, %9, off\n\t"
        "global_load_dwordx4 %3, %9, off offset:64\n\t"
        "global_load_dwordx4 %4, %10, off\n\t"
        "global_load_dwordx4 %5, %10, off offset:64\n\t"
        "global_load_dwordx4 %6, %11, off\n\t"
        "global_load_dwordx4 %7, %11, off offset:64\n\t"
        "s_waitcnt vmcnt(0)"
        : "=&v"(gv[0]), "=&v"(gv[1]), "=&v"(gv[2]), "=&v"(gv[3]),
          "=&v"(gv[4]), "=&v"(gv[5]), "=&v"(gv[6]), "=&v"(gv[7])
        : "v"(a00), "v"(a01), "v"(a10), "v"(a11)
        : "memory");
#pragma unroll
    for (int s = 0; s < 2; ++s) {
      h8 bv;
#pragma unroll
      for (int j2 = 0; j2 < 4; ++j2) {
        h2 a  = {gv[0 + s][2 * j2], gv[0 + s][2 * j2 + 1]};
        h2 bb = {gv[2 + s][2 * j2], gv[2 + s][2 * j2 + 1]};
        h2 cc = {gv[4 + s][2 * j2], gv[4 + s][2 * j2 + 1]};
        h2 dd = {gv[6 + s][2 * j2], gv[6 + s][2 * j2 + 1]};
        h2 r = a * W00;
        r += bb * W01;
        r += cc * W10;
        r += dd * W11;
        bv[2 * j2] = r[0];
        bv[2 * j2 + 1] = r[1];
      }
      const _Float16* wp = wD + (size_t)(k * 2 + s) * 2048 + L * 8;
      acc[0] = __builtin_amdgcn_mfma_f32_16x16x32_f16(*(const h8*)(wp), bv, acc[0], 0, 0, 0);
      acc[1] = __builtin_amdgcn_mfma_f32_16x16x32_f16(*(const h8*)(wp + 512), bv, acc[1], 0, 0, 0);
      acc[2] = __builtin_amdgcn_mfma_f32_16x16x32_f16(*(const h8*)(wp + 1024), bv, acc[2], 0, 0, 0);
      acc[3] = __builtin_amdgcn_mfma_f32_16x16x32_f16(*(const h8*)(wp + 1536), bv, acc[3], 0, 0, 0);
    }
  }

  // epilogue: bias + lrelu, fp32 NCHW
#pragma unroll
  for (int mt = 0; mt < 4; ++mt)
#pragma unroll
    for (int r = 0; r < 4; ++r) {
      int oc = mt * 16 + lq * 4 + r;
      float v = acc[mt][r] + bd[oc];
      v = (v >= 0.f) ? v : 0.1f * v;
      out[(((b << 6) + oc) << 14) + (y << 7) + gpx] = v;
    }
}

extern "C" void kernel_launch(void* const* d_in, const int* in_sizes, int n_in,
                              void* d_out, int out_size, void* d_ws, size_t ws_size,
                              hipStream_t stream) {
  const float* nbr   = (const float*)d_in[0];
  const float* refp  = (const float*)d_in[1];
  const float* w1    = (const float*)d_in[2];
  const float* b1    = (const float*)d_in[3];
  const float* w2    = (const float*)d_in[4];
  const float* b2    = (const float*)d_in[5];
  const float* w3    = (const float*)d_in[6];
  const float* b3    = (const float*)d_in[7];
  const float* w_off = (const float*)d_in[8];
  const float* b_off = (const float*)d_in[9];
  const float* w_dcn = (const float*)d_in[10];
  const float* b_dcn = (const float*)d_in[11];

  float* outp = (float*)d_out;
  float* feat = outp;                       // 4*64*16384
  float* offp = outp + 4194304;             // 4*18*16384
  float* mskp = outp + 4194304 + 1179648;   // 4*9*16384

  // ws layout: four padded NHWC f16 buffers [4][130][130][64] + f16 weights (~33.4 MiB)
  char* ws = (char*)d_ws;
  const size_t PB = 8652800;                // bytes per padded buffer
  _Float16* X1  = (_Float16*)ws;            // nbr padded (conv1 in + DCN sample src)
  _Float16* X2  = (_Float16*)(ws + PB);     // ref padded
  _Float16* B64 = (_Float16*)(ws + 2 * PB); // conv1 out / conv3 out
  _Float16* C64 = (_Float16*)(ws + 3 * PB); // conv2 out
  char* p = ws + 4 * PB;
  _Float16* wF1 = (_Float16*)p;  p += (size_t)73728 * 2;
  _Float16* wF2 = (_Float16*)p;  p += (size_t)36864 * 2;
  _Float16* wF3 = (_Float16*)p;  p += (size_t)36864 * 2;
  _Float16* wFo = (_Float16*)p;  p += (size_t)18432 * 2;
  _Float16* wFd = (_Float16*)p;

  // 5 dispatches total
  setup_kernel<<<dim3(3098), 256, 0, stream>>>(nbr, refp, w1, w2, w3, w_off, w_dcn,
                                               X1, X2, B64, C64, wF1, wF2, wF3, wFo, wFd);
  conv3x3_lds_kernel<4, true><<<dim3(1024), 512, 0, stream>>>(X1, X2, wF1, b1, B64);
  conv3x3_lds_kernel<2, false><<<dim3(1024), 512, 0, stream>>>(B64, nullptr, wF2, b2, C64);
  conv3x3_lds_kernel<2, false><<<dim3(1024), 512, 0, stream>>>(C64, nullptr, wF3, b3, B64);
  off_dcn_kernel<<<dim3(1024), 256, 0, stream>>>(B64, X1, wFo, b_off, wFd, b_dcn,
                                                 offp, mskp, feat);
}